// Round 10
// baseline (61.139 us; speedup 1.0000x reference)
//
#include <hip/hip_runtime.h>

#define B_     64
#define KDIM   2304
#define NCOL   1470
#define NCELL  3136   // 64 * 7 * 7
#define CPAD   1536
#define SPLITK 16
#define KCHUNK 144    // KDIM / SPLITK
#define NSTAGE 9      // KCHUNK / 16
#define XS     68     // sx row stride (writes 2-way free, reads broadcast)
#define WSD    100    // sw col stride (writes 2-way free, reads conflict-free)
#define NBLK2  392    // combine grid: NCELL / 8
#define NMS_T  256
#define QMAX   13     // ceil(NCELL / NMS_T)
#define OUTSZ  (2 * NCELL * 25)

// ---------------------------------------------------------------------------
// GEMM: partial[kc][row][col] = sum_{k in chunk} x[row][k] * W[col][k]
// Grid (16 col-tiles of 96, 16 K-chunks) = 256 blocks = 1 per CU.
// Micro-tile 8 rows x 3 cols (cols strided 32: conflict-free LDS reads).
// Double-buffered LDS, register prefetch, one barrier per stage.
// Also: zero-fills `out` (final output is zero except NMS-picked rows) and
// resets the combine->NMS arrival counter (visible to K2 via kernel boundary).
// ---------------------------------------------------------------------------
__global__ __launch_bounds__(256) void gemm_splitk(
    const float* __restrict__ x, const float* __restrict__ W,
    float* __restrict__ partial, float* __restrict__ out,
    int* __restrict__ cnts)
{
    __shared__ float sx[2][16 * XS];
    __shared__ float sw[2][16 * WSD];

    const int t = threadIdx.x;
    if (blockIdx.x == 0 && blockIdx.y == 0 && t == 0) cnts[0] = 0;

    {   // zero the output (one float4 per thread; first 39200 global threads)
        const int gt = (blockIdx.y * 16 + blockIdx.x) * 256 + t;
        if (gt < OUTSZ / 4)
            *(float4*)&out[gt * 4] = make_float4(0.f, 0.f, 0.f, 0.f);
    }

    const int c0  = blockIdx.x * 96;
    const int k0  = blockIdx.y * KCHUNK;
    const int r8  = (t >> 5) << 3;   // 8-row group: 0,8,...,56
    const int cgi = t & 31;          // cols cgi + {0,32,64}
    const int kk0 = t & 15;
    const int g0  = t >> 4;          // 0..15

    float acc[8][3];
#pragma unroll
    for (int i = 0; i < 8; ++i)
#pragma unroll
        for (int j = 0; j < 3; ++j) acc[i][j] = 0.f;

    const float* wp[6];
#pragma unroll
    for (int p = 0; p < 6; ++p) {
        int gc = c0 + p * 16 + g0;
        if (gc >= NCOL) gc = NCOL - 1;       // clamp; garbage cols ignored downstream
        wp[p] = W + (size_t)gc * KDIM + kk0;
    }

    float xr[4], wr[6];
    {   // prologue: stage 0 -> regs -> buf0
        const int kb = k0;
#pragma unroll
        for (int p = 0; p < 4; ++p) xr[p] = x[(p * 16 + g0) * KDIM + kb + kk0];
#pragma unroll
        for (int p = 0; p < 6; ++p) wr[p] = wp[p][kb];
#pragma unroll
        for (int p = 0; p < 4; ++p) sx[0][kk0 * XS + p * 16 + g0] = xr[p];
#pragma unroll
        for (int p = 0; p < 6; ++p) sw[0][kk0 * WSD + p * 16 + g0] = wr[p];
    }

    for (int s = 0; s < NSTAGE; ++s) {
        const int cb = s & 1;
        if (s + 1 < NSTAGE) {            // issue next-stage global loads now
            const int kb = k0 + ((s + 1) << 4);
#pragma unroll
            for (int p = 0; p < 4; ++p) xr[p] = x[(p * 16 + g0) * KDIM + kb + kk0];
#pragma unroll
            for (int p = 0; p < 6; ++p) wr[p] = wp[p][kb];
        }
        __syncthreads();                 // buf[cb] writes (prev iter) visible
        const float* cx = sx[cb];
        const float* cw = sw[cb];
#pragma unroll
        for (int kk = 0; kk < 16; ++kk) {
            const float4 a0 = *(const float4*)&cx[kk * XS + r8];
            const float4 a1 = *(const float4*)&cx[kk * XS + r8 + 4];
            const float w0 = cw[kk * WSD + cgi];
            const float w1 = cw[kk * WSD + cgi + 32];
            const float w2 = cw[kk * WSD + cgi + 64];
            const float av[8] = {a0.x, a0.y, a0.z, a0.w, a1.x, a1.y, a1.z, a1.w};
#pragma unroll
            for (int i = 0; i < 8; ++i) {
                acc[i][0] = fmaf(av[i], w0, acc[i][0]);
                acc[i][1] = fmaf(av[i], w1, acc[i][1]);
                acc[i][2] = fmaf(av[i], w2, acc[i][2]);
            }
        }
        if (s + 1 < NSTAGE) {            // store prefetched regs -> other buffer
#pragma unroll
            for (int p = 0; p < 4; ++p) sx[cb ^ 1][kk0 * XS + p * 16 + g0] = xr[p];
#pragma unroll
            for (int p = 0; p < 6; ++p) sw[cb ^ 1][kk0 * WSD + p * 16 + g0] = wr[p];
        }
    }

    float* pb = partial + (size_t)blockIdx.y * (B_ * CPAD) + c0 + cgi;
#pragma unroll
    for (int i = 0; i < 8; ++i)
#pragma unroll
        for (int p = 0; p < 3; ++p)
            pb[(size_t)(r8 + i) * CPAD + 32 * p] = acc[i][p];
}

// ---------------------------------------------------------------------------
// K2: combine + decode on 392 wide blocks, then intra-kernel handoff:
// every block releases (fence -> sync -> thread0 atomic add); blocks 0 and 1
// acquire-spin until all 392 arrived, then run the O(cnt)+O(picks) NMS and
// write ONLY the picked output rows (out pre-zeroed by K1). No deadlock:
// only blocks 0/1 wait, producers never wait; ~76 KB LDS -> 2 blocks/CU so
// the whole grid is co-resident anyway.
// ---------------------------------------------------------------------------
__global__ __launch_bounds__(256) void combine_nms(
    const float* __restrict__ partial, const float* __restrict__ bias,
    float* __restrict__ labels, float* __restrict__ boxes,
    float* __restrict__ scores, int* __restrict__ valid,
    int* __restrict__ cnts, float* __restrict__ out)
{
    __shared__ float sa[8][30];
    // NMS staging (used only by blocks 0,1 after the arrival barrier)
    __shared__ float sX1[NCELL], sY1[NCELL], sX2[NCELL], sY2[NCELL];
    __shared__ float sSc[NCELL];
    __shared__ int   pickList[NCELL];
    __shared__ float rv[4];
    __shared__ int   rn[4];
    __shared__ int   pickN, npicks;

    const int t    = threadIdx.x;
    const int base = blockIdx.x * 8;             // 392 * 8 == 3136 exactly

    // ---- combine + decode (identical arithmetic to prior rounds) ----
    if (t < 240) {
        const int n   = base + t / 30;
        const int col = t % 30;
        const int row = n / 49;                  // 1470/30 = 49 cells per batch-row
        const int cr  = (n % 49) * 30 + col;
        float s = 0.f;
#pragma unroll
        for (int k = 0; k < SPLITK; ++k)
            s += partial[(size_t)k * (B_ * CPAD) + (size_t)row * CPAD + cr];
        s += bias[cr];
        sa[t / 30][col] = s;
        if (col >= 10) labels[(size_t)n * 20 + (col - 10)] = s;
    }
    __syncthreads();

    if (t < 8) {
        const int n = base + t;
        const float* a = sa[t];
        float mv = a[10]; int mi = 0;
#pragma unroll
        for (int j = 1; j < 20; ++j) {
            float v = a[10 + j];
            if (v > mv) { mv = v; mi = j; }      // strict > => first-index tie-break
        }
        const float lp = (float)mi;
        const int gx = n % 7, gy = (n / 7) % 7;
        const float cw = 1.0f / 7.0f;
        const float nx = (float)gx * cw, ny = (float)gy * cw;
#pragma unroll
        for (int sl = 0; sl < 2; ++sl) {
            const int off = 5 * sl;
            const float bx0 = a[off], bx1 = a[off + 1];
            const float w_ = a[off + 2], h_ = a[off + 3];
            const float sc = a[off + 5];         // faithful port quirk: off+5
            const float cx = bx0 * cw + nx, cy = bx1 * cw + ny;
            const float X1 = cx - 0.5f * w_, Y1 = cy - 0.5f * h_;
            const float X2 = cx + 0.5f * w_, Y2 = cy + 0.5f * h_;
            const int m = sl * NCELL + n;
            boxes[m * 4 + 0] = X1 - 0.5f * X2;
            boxes[m * 4 + 1] = Y1 - 0.5f * Y2;
            boxes[m * 4 + 2] = X1 + 0.5f * X2;
            boxes[m * 4 + 3] = Y1 + 0.5f * Y2;
            scores[m] = sc;
            valid[m] = (sc * lp > 0.5f) ? 1 : 0;
        }
    }

    // ---- release: my block's writes are device-visible, then count arrival ----
    __threadfence();                             // per-thread, before the sync
    __syncthreads();
    if (t == 0)
        __hip_atomic_fetch_add(&cnts[0], 1, __ATOMIC_RELEASE, __HIP_MEMORY_SCOPE_AGENT);

    if (blockIdx.x >= 2) return;                 // producers done

    // ---- acquire: wait for all 392 blocks ----
    if (t == 0) {
        while (__hip_atomic_load(&cnts[0], __ATOMIC_ACQUIRE, __HIP_MEMORY_SCOPE_AGENT) < NBLK2) {}
    }
    __syncthreads();
    __threadfence();

    // ---- inverted greedy NMS (register bitmask) + picked-row writes ----
    const int slot = blockIdx.x;
    const int nb   = slot * NCELL;

    if (t == 0) npicks = 0;
    unsigned am = 0;                     // alive bitmask for my <=13 entries
#pragma unroll
    for (int q = 0; q < QMAX; ++q) {
        const int n = t + q * NMS_T;
        if (n < NCELL) {
            const float4 bb = *(const float4*)&boxes[(size_t)(nb + n) * 4];
            sX1[n] = bb.x; sY1[n] = bb.y; sX2[n] = bb.z; sY2[n] = bb.w;
            sSc[n] = scores[nb + n];
            if (valid[nb + n]) am |= 1u << q;
        }
    }
    __syncthreads();

    for (;;) {
        // ---- argmax over alive: (score desc, index asc) ----
        float bv = -1e30f; int bn = 0x7fffffff;
#pragma unroll
        for (int q = 0; q < QMAX; ++q)
            if ((am >> q) & 1u) {
                const int n = t + q * NMS_T;
                const float v = sSc[n];
                if (v > bv || (v == bv && n < bn)) { bv = v; bn = n; }
            }
#pragma unroll
        for (int o = 32; o > 0; o >>= 1) {
            const float ov = __shfl_down(bv, o);
            const int   on = __shfl_down(bn, o);
            if (ov > bv || (ov == bv && on < bn)) { bv = ov; bn = on; }
        }
        if ((t & 63) == 0) { rv[t >> 6] = bv; rn[t >> 6] = bn; }
        __syncthreads();
        if (t == 0) {
            float v2 = rv[0]; int n2 = rn[0];
#pragma unroll
            for (int q = 1; q < 4; ++q)
                if (rv[q] > v2 || (rv[q] == v2 && rn[q] < n2)) { v2 = rv[q]; n2 = rn[q]; }
            if (v2 == -1e30f) { pickN = -1; }
            else { pickN = n2; pickList[npicks++] = n2; }
        }
        __syncthreads();
        const int pn = pickN;
        if (pn < 0) break;
        const float px1 = sX1[pn], py1 = sY1[pn], px2 = sX2[pn], py2 = sY2[pn];
        const float pa = (px2 - px1) * (py2 - py1);

        // ---- retain only entries with IoU >= 0.5 vs pick (and not pick) ----
#pragma unroll
        for (int q = 0; q < QMAX; ++q)
            if ((am >> q) & 1u) {
                const int n = t + q * NMS_T;
                const float x1 = sX1[n], y1 = sY1[n], x2 = sX2[n], y2 = sY2[n];
                const float an = (x2 - x1) * (y2 - y1);
                const float ix1 = fmaxf(x1, px1), iy1 = fmaxf(y1, py1);
                const float ix2 = fminf(x2, px2), iy2 = fminf(y2, py2);
                const float inter = fmaxf(ix2 - ix1, 0.f) * fmaxf(iy2 - iy1, 0.f);
                const float iou = inter / (pa + an - inter);   // IEEE divide
                if (!(iou >= 0.5f) || n == pn) am &= ~(1u << q);
            }
        // next iteration's barriers order rv/pick reuse
    }

    // ---- write ONLY the picked rows: [boxes*448, score, labels(20)] ----
    const int np = npicks;
    for (int u = t; u < np * 25; u += NMS_T) {
        const int pi = u / 25;
        const int c  = u % 25;
        const int n  = pickList[pi];
        float v;
        if (c < 4)       v = (c == 0 ? sX1[n] : c == 1 ? sY1[n] : c == 2 ? sX2[n] : sY2[n]) * 448.0f;
        else if (c == 4) v = sSc[n];
        else             v = labels[(size_t)n * 20 + (c - 5)];
        out[(size_t)(nb + n) * 25 + c] = v;
    }
}

// ---------------------------------------------------------------------------
extern "C" void kernel_launch(void* const* d_in, const int* in_sizes, int n_in,
                              void* d_out, int out_size, void* d_ws, size_t ws_size,
                              hipStream_t stream)
{
    const float* x = (const float*)d_in[0];
    const float* W = (const float*)d_in[1];
    const float* b = (const float*)d_in[2];
    float* out = (float*)d_out;

    float* ws      = (float*)d_ws;
    float* partial = ws;                                        // 16*64*1536
    float* labels  = partial + (size_t)SPLITK * B_ * CPAD;      // 3136*20
    float* boxes   = labels + (size_t)NCELL * 20;               // 3136*8
    float* scores  = boxes + (size_t)NCELL * 8;                 // 3136*2
    int*   valid   = (int*)(scores + (size_t)NCELL * 2);        // 3136*2
    int*   cnts    = valid + (size_t)NCELL * 2;                 // 2

    hipLaunchKernelGGL(gemm_splitk, dim3(16, SPLITK), dim3(256), 0, stream,
                       x, W, partial, out, cnts);
    hipLaunchKernelGGL(combine_nms, dim3(NBLK2), dim3(256), 0, stream,
                       partial, b, labels, boxes, scores, valid, cnts, out);
}

// Round 11
// 31.119 us; speedup vs baseline: 1.9647x; 1.9647x over previous
//
#include <hip/hip_runtime.h>

#define B_     64
#define KDIM   2304
#define NCOL   1470
#define NCELL  3136   // 64 * 7 * 7
#define CPAD   1536
#define SPLITK 16
#define KCHUNK 144    // KDIM / SPLITK
#define NSTAGE 9      // KCHUNK / 16
#define XS     68     // sx row stride (writes 2-way free, reads broadcast)
#define WSD    100    // sw col stride (writes 2-way free, reads conflict-free)
#define NMS_T  1024
#define QMAX   4      // ceil(NCELL / NMS_T)
#define OUTSZ  (2 * NCELL * 25)

// ---------------------------------------------------------------------------
// GEMM: partial[kc][row][col] = sum_{k in chunk} x[row][k] * W[col][k]
// Grid (16 col-tiles of 96, 16 K-chunks) = 256 blocks = 1 per CU.
// Micro-tile 8 rows x 3 cols (cols strided 32: conflict-free LDS reads).
// Double-buffered LDS, register prefetch, one barrier per stage.
// Also zero-fills `out` (final output is zero except NMS-picked rows,
// written later by nms_pick): 39200 float4 stores spread over 65536 threads,
// issued up front so they hide under the prologue's global-load latency.
// NO cross-block sync/atomics anywhere (rounds 3/7/10 lesson: they cost
// more than the launch gaps they'd remove).
// ---------------------------------------------------------------------------
__global__ __launch_bounds__(256) void gemm_splitk(
    const float* __restrict__ x, const float* __restrict__ W,
    float* __restrict__ partial, float* __restrict__ out)
{
    __shared__ float sx[2][16 * XS];
    __shared__ float sw[2][16 * WSD];

    const int t = threadIdx.x;

    {   // zero the output (one float4 per thread; first 39200 global threads)
        const int gt = (blockIdx.y * 16 + blockIdx.x) * 256 + t;
        if (gt < OUTSZ / 4)
            *(float4*)&out[gt * 4] = make_float4(0.f, 0.f, 0.f, 0.f);
    }

    const int c0  = blockIdx.x * 96;
    const int k0  = blockIdx.y * KCHUNK;
    const int r8  = (t >> 5) << 3;   // 8-row group: 0,8,...,56
    const int cgi = t & 31;          // cols cgi + {0,32,64}
    const int kk0 = t & 15;
    const int g0  = t >> 4;          // 0..15

    float acc[8][3];
#pragma unroll
    for (int i = 0; i < 8; ++i)
#pragma unroll
        for (int j = 0; j < 3; ++j) acc[i][j] = 0.f;

    const float* wp[6];
#pragma unroll
    for (int p = 0; p < 6; ++p) {
        int gc = c0 + p * 16 + g0;
        if (gc >= NCOL) gc = NCOL - 1;       // clamp; garbage cols ignored downstream
        wp[p] = W + (size_t)gc * KDIM + kk0;
    }

    float xr[4], wr[6];
    {   // prologue: stage 0 -> regs -> buf0
        const int kb = k0;
#pragma unroll
        for (int p = 0; p < 4; ++p) xr[p] = x[(p * 16 + g0) * KDIM + kb + kk0];
#pragma unroll
        for (int p = 0; p < 6; ++p) wr[p] = wp[p][kb];
#pragma unroll
        for (int p = 0; p < 4; ++p) sx[0][kk0 * XS + p * 16 + g0] = xr[p];
#pragma unroll
        for (int p = 0; p < 6; ++p) sw[0][kk0 * WSD + p * 16 + g0] = wr[p];
    }

    for (int s = 0; s < NSTAGE; ++s) {
        const int cb = s & 1;
        if (s + 1 < NSTAGE) {            // issue next-stage global loads now
            const int kb = k0 + ((s + 1) << 4);
#pragma unroll
            for (int p = 0; p < 4; ++p) xr[p] = x[(p * 16 + g0) * KDIM + kb + kk0];
#pragma unroll
            for (int p = 0; p < 6; ++p) wr[p] = wp[p][kb];
        }
        __syncthreads();                 // buf[cb] writes (prev iter) visible
        const float* cx = sx[cb];
        const float* cw = sw[cb];
#pragma unroll
        for (int kk = 0; kk < 16; ++kk) {
            const float4 a0 = *(const float4*)&cx[kk * XS + r8];
            const float4 a1 = *(const float4*)&cx[kk * XS + r8 + 4];
            const float w0 = cw[kk * WSD + cgi];
            const float w1 = cw[kk * WSD + cgi + 32];
            const float w2 = cw[kk * WSD + cgi + 64];
            const float av[8] = {a0.x, a0.y, a0.z, a0.w, a1.x, a1.y, a1.z, a1.w};
#pragma unroll
            for (int i = 0; i < 8; ++i) {
                acc[i][0] = fmaf(av[i], w0, acc[i][0]);
                acc[i][1] = fmaf(av[i], w1, acc[i][1]);
                acc[i][2] = fmaf(av[i], w2, acc[i][2]);
            }
        }
        if (s + 1 < NSTAGE) {            // store prefetched regs -> other buffer
#pragma unroll
            for (int p = 0; p < 4; ++p) sx[cb ^ 1][kk0 * XS + p * 16 + g0] = xr[p];
#pragma unroll
            for (int p = 0; p < 6; ++p) sw[cb ^ 1][kk0 * WSD + p * 16 + g0] = wr[p];
        }
    }

    float* pb = partial + (size_t)blockIdx.y * (B_ * CPAD) + c0 + cgi;
#pragma unroll
    for (int i = 0; i < 8; ++i)
#pragma unroll
        for (int p = 0; p < 3; ++p)
            pb[(size_t)(r8 + i) * CPAD + 32 * p] = acc[i][p];
}

// ---------------------------------------------------------------------------
// Fused split-K combine + bias + per-cell decode (8 cells per 256-thr block).
// Dense outputs, NO atomics: labels[n*20], boxes[m*4], scores[m], valid[m].
// ---------------------------------------------------------------------------
__global__ __launch_bounds__(256) void combine_prep(
    const float* __restrict__ partial, const float* __restrict__ bias,
    float* __restrict__ labels, float* __restrict__ boxes,
    float* __restrict__ scores, int* __restrict__ valid)
{
    __shared__ float sa[8][30];
    const int t    = threadIdx.x;
    const int base = blockIdx.x * 8;             // 392 * 8 == 3136 exactly

    if (t < 240) {
        const int n   = base + t / 30;
        const int col = t % 30;
        const int row = n / 49;                  // 1470/30 = 49 cells per batch-row
        const int cr  = (n % 49) * 30 + col;
        float s = 0.f;
#pragma unroll
        for (int k = 0; k < SPLITK; ++k)
            s += partial[(size_t)k * (B_ * CPAD) + (size_t)row * CPAD + cr];
        s += bias[cr];
        sa[t / 30][col] = s;
        if (col >= 10) labels[(size_t)n * 20 + (col - 10)] = s;
    }
    __syncthreads();

    if (t < 8) {
        const int n = base + t;
        const float* a = sa[t];
        float mv = a[10]; int mi = 0;
#pragma unroll
        for (int j = 1; j < 20; ++j) {
            float v = a[10 + j];
            if (v > mv) { mv = v; mi = j; }      // strict > => first-index tie-break
        }
        const float lp = (float)mi;
        const int gx = n % 7, gy = (n / 7) % 7;
        const float cw = 1.0f / 7.0f;
        const float nx = (float)gx * cw, ny = (float)gy * cw;
#pragma unroll
        for (int sl = 0; sl < 2; ++sl) {
            const int off = 5 * sl;
            const float bx0 = a[off], bx1 = a[off + 1];
            const float w_ = a[off + 2], h_ = a[off + 3];
            const float sc = a[off + 5];         // faithful port quirk: off+5
            const float cx = bx0 * cw + nx, cy = bx1 * cw + ny;
            const float X1 = cx - 0.5f * w_, Y1 = cy - 0.5f * h_;
            const float X2 = cx + 0.5f * w_, Y2 = cy + 0.5f * h_;
            const int m = sl * NCELL + n;
            boxes[m * 4 + 0] = X1 - 0.5f * X2;
            boxes[m * 4 + 1] = Y1 - 0.5f * Y2;
            boxes[m * 4 + 2] = X1 + 0.5f * X2;
            boxes[m * 4 + 3] = Y1 + 0.5f * Y2;
            scores[m] = sc;
            valid[m] = (sc * lp > 0.5f) ? 1 : 0;
        }
    }
}

// ---------------------------------------------------------------------------
// Inverted greedy NMS + direct write of the (few) picked output rows.
// One 1024-thread block per slot. LDS SoA staging (~75 KB); alive set =
// 4 bits/thread register bitmask; 2 barriers per pick; no atomics.
// Output was pre-zeroed by gemm_splitk, so ONLY picked rows are written:
// O(picks) stores + O(picks*20) label gathers — legal narrow-phase work.
// ---------------------------------------------------------------------------
__global__ __launch_bounds__(NMS_T) void nms_pick(
    const float* __restrict__ boxes, const float* __restrict__ scores,
    const int* __restrict__ valid, const float* __restrict__ labels,
    float* __restrict__ out)
{
    __shared__ float sX1[NCELL], sY1[NCELL], sX2[NCELL], sY2[NCELL];
    __shared__ float sSc[NCELL];
    __shared__ int   pickList[NCELL];
    __shared__ float rv[16];
    __shared__ int   rn[16];
    __shared__ int   pickN, npicks;

    const int slot = blockIdx.x;
    const int base = slot * NCELL;
    const int t = threadIdx.x;

    if (t == 0) npicks = 0;
    unsigned am = 0;                     // alive bitmask for my <=4 entries
#pragma unroll
    for (int q = 0; q < QMAX; ++q) {
        const int n = t + q * NMS_T;
        if (n < NCELL) {
            const float4 bb = *(const float4*)&boxes[(size_t)(base + n) * 4];
            sX1[n] = bb.x; sY1[n] = bb.y; sX2[n] = bb.z; sY2[n] = bb.w;
            sSc[n] = scores[base + n];
            if (valid[base + n]) am |= 1u << q;
        }
    }
    __syncthreads();

    for (;;) {
        // ---- argmax over alive: (score desc, index asc) ----
        float bv = -1e30f; int bn = 0x7fffffff;
#pragma unroll
        for (int q = 0; q < QMAX; ++q)
            if ((am >> q) & 1u) {
                const int n = t + q * NMS_T;
                const float v = sSc[n];
                if (v > bv || (v == bv && n < bn)) { bv = v; bn = n; }
            }
#pragma unroll
        for (int o = 32; o > 0; o >>= 1) {
            const float ov = __shfl_down(bv, o);
            const int   on = __shfl_down(bn, o);
            if (ov > bv || (ov == bv && on < bn)) { bv = ov; bn = on; }
        }
        if ((t & 63) == 0) { rv[t >> 6] = bv; rn[t >> 6] = bn; }
        __syncthreads();
        if (t == 0) {
            float v2 = rv[0]; int n2 = rn[0];
#pragma unroll
            for (int q = 1; q < 16; ++q)
                if (rv[q] > v2 || (rv[q] == v2 && rn[q] < n2)) { v2 = rv[q]; n2 = rn[q]; }
            if (v2 == -1e30f) { pickN = -1; }
            else { pickN = n2; pickList[npicks++] = n2; }
        }
        __syncthreads();
        const int pn = pickN;
        if (pn < 0) break;
        const float px1 = sX1[pn], py1 = sY1[pn], px2 = sX2[pn], py2 = sY2[pn];
        const float pa = (px2 - px1) * (py2 - py1);

        // ---- retain only entries with IoU >= 0.5 vs pick (and not pick) ----
#pragma unroll
        for (int q = 0; q < QMAX; ++q)
            if ((am >> q) & 1u) {
                const int n = t + q * NMS_T;
                const float x1 = sX1[n], y1 = sY1[n], x2 = sX2[n], y2 = sY2[n];
                const float an = (x2 - x1) * (y2 - y1);
                const float ix1 = fmaxf(x1, px1), iy1 = fmaxf(y1, py1);
                const float ix2 = fminf(x2, px2), iy2 = fminf(y2, py2);
                const float inter = fmaxf(ix2 - ix1, 0.f) * fmaxf(iy2 - iy1, 0.f);
                const float iou = inter / (pa + an - inter);   // IEEE divide
                if (!(iou >= 0.5f) || n == pn) am &= ~(1u << q);
            }
        // next iteration's barriers order rv/pick reuse
    }

    // ---- write ONLY the picked rows: [boxes*448, score, labels(20)] ----
    const int np = npicks;
    for (int u = t; u < np * 25; u += NMS_T) {
        const int pi = u / 25;
        const int c  = u % 25;
        const int n  = pickList[pi];
        float v;
        if (c < 4)       v = (c == 0 ? sX1[n] : c == 1 ? sY1[n] : c == 2 ? sX2[n] : sY2[n]) * 448.0f;
        else if (c == 4) v = sSc[n];
        else             v = labels[(size_t)n * 20 + (c - 5)];
        out[(size_t)(base + n) * 25 + c] = v;
    }
}

// ---------------------------------------------------------------------------
extern "C" void kernel_launch(void* const* d_in, const int* in_sizes, int n_in,
                              void* d_out, int out_size, void* d_ws, size_t ws_size,
                              hipStream_t stream)
{
    const float* x = (const float*)d_in[0];
    const float* W = (const float*)d_in[1];
    const float* b = (const float*)d_in[2];
    float* out = (float*)d_out;

    float* ws      = (float*)d_ws;
    float* partial = ws;                                        // 16*64*1536
    float* labels  = partial + (size_t)SPLITK * B_ * CPAD;      // 3136*20
    float* boxes   = labels + (size_t)NCELL * 20;               // 3136*8
    float* scores  = boxes + (size_t)NCELL * 8;                 // 3136*2
    int*   valid   = (int*)(scores + (size_t)NCELL * 2);        // 3136*2

    hipLaunchKernelGGL(gemm_splitk, dim3(16, SPLITK), dim3(256), 0, stream,
                       x, W, partial, out);
    hipLaunchKernelGGL(combine_prep, dim3(NCELL / 8), dim3(256), 0, stream,
                       partial, b, labels, boxes, scores, valid);
    hipLaunchKernelGGL(nms_pick, dim3(2), dim3(NMS_T), 0, stream,
                       boxes, scores, valid, labels, out);
}